// Round 1
// baseline (443.469 us; speedup 1.0000x reference)
//
#include <hip/hip_runtime.h>

// DecorrelationNormalization (group whitening), x: [32,64,64,256] f32 NHWC.
// N = 131072 rows, C = 256 channels, 16 groups of m=16.
// Phase 1: per-group sums  (Sx[16], Sxx triangle[136])  -- 1 read of x
// Phase 2: cov -> cholesky -> L^{-1} -> bias  (16 tiny 16x16, 1 wave/group)
// Phase 3: out = L^{-1} (x - mu) = L^{-1} x - bias      -- read x + write out

#define NROWS   131072
#define DENOMF  131071.0f
#define EPSV    0.001f

// workspace float offsets
#define OFF_TRI  0        // [16][136] Sxx upper-triangle sums
#define OFF_SX   2176     // [256] channel sums
#define OFF_INV  2432     // [16][16][16] inv_sqrt rows (upper filled w/ 0)
#define OFF_BIAS 6528     // [16][16] bias_i = sum_k inv[i][k]*mu[k]
#define ACC_FLOATS 2432   // region that must be zeroed before k1

__device__ __forceinline__ float wave_reduce64(float v, int /*lane*/) {
    v += __shfl_xor(v, 32, 64);
    v += __shfl_xor(v, 16, 64);
    v += __shfl_xor(v, 8, 64);
    v += __shfl_xor(v, 4, 64);
    v += __shfl_xor(v, 2, 64);
    v += __shfl_xor(v, 1, 64);
    return v;
}

// ---------------- Phase 1: stats ----------------
// grid 512 blocks x 256 thr = 2048 waves; wave W: group g = W&15, row-tile wt = W>>4 (0..127)
// rows n = wt*1024 + pass*64 + lane, 16 passes.
__global__ __launch_bounds__(256, 2) void k1_stats(const float* __restrict__ x,
                                                   float* __restrict__ ws) {
    const int tid  = threadIdx.x;
    const int wv   = tid >> 6;
    const int lane = tid & 63;
    const int W    = blockIdx.x * 4 + wv;
    const int g    = W & 15;
    const int wt   = W >> 4;
    const float* xg = x + g * 16;

    float acc[136];
    float s[16];
#pragma unroll
    for (int p = 0; p < 136; ++p) acc[p] = 0.0f;
#pragma unroll
    for (int k = 0; k < 16; ++k) s[k] = 0.0f;

    for (int pass = 0; pass < 16; ++pass) {
        size_t n = (size_t)wt * 1024 + (size_t)pass * 64 + lane;
        const float4* p4 = reinterpret_cast<const float4*>(xg + n * 256);
        float4 a = p4[0], b = p4[1], c = p4[2], d = p4[3];
        float v[16] = {a.x, a.y, a.z, a.w, b.x, b.y, b.z, b.w,
                       c.x, c.y, c.z, c.w, d.x, d.y, d.z, d.w};
#pragma unroll
        for (int k = 0; k < 16; ++k) s[k] += v[k];
#pragma unroll
        for (int i = 0; i < 16; ++i) {
#pragma unroll
            for (int j = i; j < 16; ++j) {
                const int idx = i * 16 - (i * (i - 1)) / 2 + (j - i);
                acc[idx] = fmaf(v[i], v[j], acc[idx]);
            }
        }
    }

    // cross-lane reduce + atomic accumulate (one lane per entry)
#pragma unroll
    for (int p = 0; p < 136; ++p) {
        float v = wave_reduce64(acc[p], lane);
        if (lane == (p & 63)) atomicAdd(&ws[OFF_TRI + g * 136 + p], v);
    }
#pragma unroll
    for (int k = 0; k < 16; ++k) {
        float v = wave_reduce64(s[k], lane);
        if (lane == k) atomicAdd(&ws[OFF_SX + g * 16 + k], v);
    }
}

// ---------------- Phase 2: cov -> cholesky -> inverse -> bias ----------------
// 16 blocks (one group each) x 64 threads. Lanes 0..15 active-ish:
//  - cholesky: lane ii owns row ii of A/L
//  - solve:    lane ii owns column ii of X = L^{-1}
__global__ void k2_chol(float* __restrict__ ws) {
    const int g    = blockIdx.x;
    const int lane = threadIdx.x;
    const int ii   = lane & 15;           // lanes 16..63 duplicate rows, writes guarded
    const float* tri = ws + OFF_TRI + g * 136;
    const float* sx  = ws + OFF_SX + g * 16;
    const float inv_denom = 1.0f / DENOMF;

    const float mu_l = sx[ii] * (1.0f / (float)NROWS);
    const float mu_i = mu_l;

    // build row ii of cov (after shrinkage and the faithful second /denom)
    float arow[16];
#pragma unroll
    for (int k = 0; k < 16; ++k) {
        const int lo = (ii < k) ? ii : k;
        const int hi = (ii < k) ? k : ii;
        float sxx = tri[lo * 16 - (lo * (lo - 1)) / 2 + (hi - lo)];
        float mu_k = __shfl(mu_l, k, 64);
        float cv = (sxx - (float)NROWS * mu_i * mu_k) * inv_denom;   // C1
        cv = cv * (1.0f - EPSV) + ((k == ii) ? EPSV : 0.0f);         // shrink
        arow[k] = cv * inv_denom;                                    // second /denom
    }

    // cholesky, lane-per-row (right-looking)
    float lrow[16];
#pragma unroll
    for (int j = 0; j < 16; ++j) {
        float diag = __shfl(arow[j], j, 64);
        float ljj  = sqrtf(diag);
        float lij  = (ii == j) ? ljj : arow[j] / ljj;
        lrow[j] = lij;
#pragma unroll
        for (int k = j + 1; k < 16; ++k) {
            float lkj = __shfl(lij, k, 64);
            arow[k] = fmaf(-lij, lkj, arow[k]);
        }
    }

    // X = L^{-1}, lane-per-column (forward substitution)
    float xcol[16];
#pragma unroll
    for (int i2 = 0; i2 < 16; ++i2) {
        float ssum = (ii == i2) ? 1.0f : 0.0f;
#pragma unroll
        for (int k = 0; k < 16; ++k) {
            if (k < i2) {                       // static prune
                float Lik = __shfl(lrow[k], i2, 64);
                ssum = fmaf(-Lik, xcol[k], ssum);   // xcol[k]==0 for k<ii
            }
        }
        float Lii = __shfl(lrow[i2], i2, 64);
        xcol[i2] = (i2 >= ii) ? ssum / Lii : 0.0f;
    }

    // write inv (row-major, zeros above diag) + bias_i = sum_j inv[i][j]*mu_j
    float* invg = ws + OFF_INV + g * 256;
#pragma unroll
    for (int i2 = 0; i2 < 16; ++i2) {
        if (lane < 16) invg[i2 * 16 + lane] = xcol[i2];
        float bi = xcol[i2] * mu_l;
        bi += __shfl_xor(bi, 1, 64);
        bi += __shfl_xor(bi, 2, 64);
        bi += __shfl_xor(bi, 4, 64);
        bi += __shfl_xor(bi, 8, 64);
        if (lane == 0) ws[OFF_BIAS + g * 16 + i2] = bi;
    }
}

// ---------------- Phase 3: apply out = inv*x - bias ----------------
// grid 1024 blocks x 256 thr = 4096 waves; wave W: g = W&15, wt = W>>4 (0..255)
// rows n = wt*512 + pass*64 + lane, 8 passes.
__global__ __launch_bounds__(256, 4) void k3_apply(const float* __restrict__ x,
                                                   const float* __restrict__ ws,
                                                   float* __restrict__ out) {
    __shared__ float4 sinv[4][64];   // per-wave group inv, float4-packed
    __shared__ float  sbias[4][16];

    const int tid  = threadIdx.x;
    const int wv   = tid >> 6;
    const int lane = tid & 63;
    const int W    = blockIdx.x * 4 + wv;
    const int g    = W & 15;
    const int wt   = W >> 4;

    sinv[wv][lane] = reinterpret_cast<const float4*>(ws + OFF_INV + g * 256)[lane];
    if (lane < 16) sbias[wv][lane] = ws[OFF_BIAS + g * 16 + lane];
    __syncthreads();

    const float4* sv = sinv[wv];
    const float*  sb = sbias[wv];

    for (int pass = 0; pass < 8; ++pass) {
        size_t n = (size_t)wt * 512 + (size_t)pass * 64 + lane;
        const float4* p4 = reinterpret_cast<const float4*>(x + n * 256 + g * 16);
        float4 a = p4[0], b = p4[1], c = p4[2], d = p4[3];
        float v[16] = {a.x, a.y, a.z, a.w, b.x, b.y, b.z, b.w,
                       c.x, c.y, c.z, c.w, d.x, d.y, d.z, d.w};
        float o[16];
#pragma unroll
        for (int i2 = 0; i2 < 16; ++i2) {
            float ssum = -sb[i2];
#pragma unroll
            for (int kq = 0; kq < 4; ++kq) {
                if (kq <= (i2 >> 2)) {          // static prune: inv upper = 0 anyway
                    float4 lv = sv[i2 * 4 + kq];
                    ssum = fmaf(lv.x, v[kq * 4 + 0], ssum);
                    ssum = fmaf(lv.y, v[kq * 4 + 1], ssum);
                    ssum = fmaf(lv.z, v[kq * 4 + 2], ssum);
                    ssum = fmaf(lv.w, v[kq * 4 + 3], ssum);
                }
            }
            o[i2] = ssum;
        }
        float4* q4 = reinterpret_cast<float4*>(out + n * 256 + g * 16);
        q4[0] = make_float4(o[0],  o[1],  o[2],  o[3]);
        q4[1] = make_float4(o[4],  o[5],  o[6],  o[7]);
        q4[2] = make_float4(o[8],  o[9],  o[10], o[11]);
        q4[3] = make_float4(o[12], o[13], o[14], o[15]);
    }
}

extern "C" void kernel_launch(void* const* d_in, const int* in_sizes, int n_in,
                              void* d_out, int out_size, void* d_ws, size_t ws_size,
                              hipStream_t stream) {
    const float* x = (const float*)d_in[0];
    float* out = (float*)d_out;
    float* ws  = (float*)d_ws;

    // zero the atomic accumulator region every call (ws is poisoned once, never re-poisoned)
    hipMemsetAsync(ws, 0, ACC_FLOATS * sizeof(float), stream);

    k1_stats<<<512, 256, 0, stream>>>(x, ws);
    k2_chol <<<16,  64,  0, stream>>>(ws);
    k3_apply<<<1024, 256, 0, stream>>>(x, ws, out);
}